// Round 5
// baseline (437.984 us; speedup 1.0000x reference)
//
#include <hip/hip_runtime.h>
#include <hip/hip_bf16.h>
#include <cstdint>
#include <cstddef>

// Problem constants (reference: BATCH,SEQ,HIDDEN,N_TYPES = 8,1024,256,4; MAX_SPAN=12)
#define BATCH   8
#define SEQLEN  1024
#define HIDDEN  256
#define NTYPES  4
#define NSPAN   12222   // 1013*12 + (11+...+1)
#define NFULL   12156   // 1013*12 (spans with full 12-length runs)
#define NPAD    12288   // 96 tiles * 128 rows (legacy path)
#define KDIM    512     // 2*HIDDEN
#define NCOL    1024    // NTYPES*HIDDEN
#define MROWS   8192    // BATCH*SEQLEN
#define PCOLS   2048    // 2*NCOL : [start-half | end-half]
#define SB      4       // s-values owned per epi block

typedef __bf16 bf16x8 __attribute__((ext_vector_type(8)));
typedef float  f32x4  __attribute__((ext_vector_type(4)));
struct alignas(8) B4 { __bf16 a, b, c, d; };

#define AS1 __attribute__((address_space(1)))
#define AS3 __attribute__((address_space(3)))

__device__ __forceinline__ void load16(const __bf16* g, __bf16* l) {
    // 16B direct global->LDS; LDS dest is wave-uniform base + lane*16.
    __builtin_amdgcn_global_load_lds((AS1 const void*)g, (AS3 void*)l, 16, 0, 0);
}

__device__ __forceinline__ f32x4 cvt4(B4 v) {
    return (f32x4){(float)v.a, (float)v.b, (float)v.c, (float)v.d};
}

// ---- fp32 -> bf16 conversion (4 elems/thread) ----
__global__ void cvt_bf16(const float* __restrict__ src, __bf16* __restrict__ dst, int n) {
    int i = (blockIdx.x * 256 + threadIdx.x) * 4;
    if (i + 3 < n) {
        float4 f = *(const float4*)(src + i);
        B4 v;
        v.a = (__bf16)f.x; v.b = (__bf16)f.y; v.c = (__bf16)f.z; v.d = (__bf16)f.w;
        *(B4*)(dst + i) = v;
    }
}

// ---- build Wcat bf16 [PCOLS][256] (n-major, k contiguous) ----
// row j' < 1024: W[t,h,0:256]; row j' >= 1024: W[t,h,256:512]; t=(j'%1024)/256, h=j'%256
__global__ void mk_wbf2(const float* __restrict__ W, __bf16* __restrict__ dst) {
    int idx = (blockIdx.x * 256 + threadIdx.x) * 4;     // j'*256 + k
    int jp = idx >> 8, k = idx & 255;
    int t = (jp & 1023) >> 8, h = jp & 255;
    int c = k + ((jp >> 10) << 8);
    float4 f = *(const float4*)(W + ((size_t)(t * 256 + h)) * 512 + c);
    B4 v;
    v.a = (__bf16)f.x; v.b = (__bf16)f.y; v.c = (__bf16)f.z; v.d = (__bf16)f.w;
    *(B4*)(dst + idx) = v;
}

// ---- P-GEMM: P[m, j] = sum_k A[m,k] * Wbf2[j,k] (+ bias[j] on start-half cols).
// K=256, N=2048, M=grid.x*128. Proven 128x128/BK=32 structure.
__global__ __launch_bounds__(256) void pgemm(
    const __bf16* __restrict__ A,     // [Mrows][256]
    const __bf16* __restrict__ Wbf2,  // [PCOLS][256]
    const float*  __restrict__ bias,  // [NCOL]
    __bf16*       __restrict__ P)     // [Mrows][PCOLS]
{
    __shared__ alignas(16) __bf16 As[128 * 32];
    __shared__ alignas(16) __bf16 Bs[128 * 32];

    const int tid  = threadIdx.x;
    const int wave = tid >> 6;
    const int lane = tid & 63;
    const int wm   = (wave >> 1) * 64;
    const int wn   = (wave & 1) * 64;
    const int lr   = lane & 15;
    const int lq   = lane >> 4;

    const int m0 = blockIdx.x * 128;     // row tiles
    const int j0 = blockIdx.y * 128;     // 16 col tiles

    const int l0  = wave * 1024 + lane * 8;
    const int l1  = l0 + 512;
    const int mm0 = l0 >> 5, kk0 = l0 & 31;
    const int mm1 = l1 >> 5, kk1 = l1 & 31;

    const __bf16* a0 = A    + (size_t)(m0 + mm0) * HIDDEN + kk0;
    const __bf16* a1 = A    + (size_t)(m0 + mm1) * HIDDEN + kk1;
    const __bf16* w0 = Wbf2 + (size_t)(j0 + mm0) * HIDDEN + kk0;
    const __bf16* w1 = Wbf2 + (size_t)(j0 + mm1) * HIDDEN + kk1;

    f32x4 acc[4][4];
#pragma unroll
    for (int i = 0; i < 4; ++i)
#pragma unroll
        for (int j = 0; j < 4; ++j)
            acc[i][j] = (f32x4){0.f, 0.f, 0.f, 0.f};

    for (int ks = 0; ks < 8; ++ks) {
        const int c0 = ks * 32;
        __syncthreads();
        load16(a0 + c0, &As[l0]);
        load16(a1 + c0, &As[l1]);
        load16(w0 + c0, &Bs[l0]);
        load16(w1 + c0, &Bs[l1]);
        __syncthreads();

        bf16x8 af[4], bfv[4];
#pragma unroll
        for (int mi = 0; mi < 4; ++mi)
            af[mi] = *(const bf16x8*)(As + (wm + mi * 16 + lr) * 32 + lq * 8);
#pragma unroll
        for (int ni = 0; ni < 4; ++ni)
            bfv[ni] = *(const bf16x8*)(Bs + (wn + ni * 16 + lr) * 32 + lq * 8);
#pragma unroll
        for (int mi = 0; mi < 4; ++mi)
#pragma unroll
            for (int ni = 0; ni < 4; ++ni)
                acc[mi][ni] = __builtin_amdgcn_mfma_f32_16x16x32_bf16(
                    af[mi], bfv[ni], acc[mi][ni], 0, 0, 0);
    }

    // bias folds into the start-half columns (j < NCOL) before bf16 rounding
    float bv[4] = {0.f, 0.f, 0.f, 0.f};
    if (j0 < NCOL) {
#pragma unroll
        for (int ni = 0; ni < 4; ++ni) bv[ni] = bias[j0 + wn + ni * 16 + lr];
    }

#pragma unroll
    for (int mi = 0; mi < 4; ++mi) {
#pragma unroll
        for (int r = 0; r < 4; ++r) {
            const int m = m0 + wm + mi * 16 + lq * 4 + r;   // C/D: row = quad*4+reg
            __bf16* op = P + (size_t)m * PCOLS + (j0 + wn + lr);
#pragma unroll
            for (int ni = 0; ni < 4; ++ni)
                op[ni * 16] = (__bf16)(acc[mi][ni][r] + bv[ni]);
        }
    }
}

// ---- epilogue, register-window form ----
// Each block owns SB=4 consecutive s values of one batch. The Pe window
// (rows s0..s0+SB+10, 15 rows) is loaded ONCE into registers (30 VGPR raw bf16)
// -> Pe read amplification drops 12x -> 3.75x BY CONSTRUCTION, independent of
// L2 / XCD-mapping luck. All array indices compile-time (full unroll).
// Writes: 48 independent non-temporal 16B stores; out rows for a full block are
// contiguous (nbase(s+1) = nbase(s)+12).
__global__ __launch_bounds__(256) void span_epi(
    const __bf16* __restrict__ P,     // [nb*SEQLEN][PCOLS]
    float*        __restrict__ out,   // [BATCH][NSPAN][NCOL]
    int b0)
{
    const int bx   = blockIdx.x;
    const int brel = bx >> 8;                // 256 blocks per batch
    const int b    = b0 + brel;
    const int s0   = (bx & 255) * SB;
    const int j    = threadIdx.x * 4;

    const __bf16* Pb = P + (size_t)brel * SEQLEN * PCOLS;

    // Ps for the SB spans (bias already folded), converted once
    f32x4 psf[SB];
#pragma unroll
    for (int t = 0; t < SB; ++t)
        psf[t] = cvt4(*(const B4*)(Pb + (size_t)(s0 + t) * PCOLS + j));

    // Pe window, clamped at the sequence end (only last 3 blocks/batch clamp)
    B4 pe[SB + 11];
#pragma unroll
    for (int t = 0; t < SB + 11; ++t) {
        int r = s0 + t;
        if (r > SEQLEN - 1) r = SEQLEN - 1;
        pe[t] = *(const B4*)(Pb + (size_t)r * PCOLS + NCOL + j);
    }

#pragma unroll
    for (int t = 0; t < SB; ++t) {
        const int s = s0 + t;
        int len; long nbase;
        if (s <= SEQLEN - 12) { len = 12; nbase = (long)s * 12; }
        else { len = SEQLEN - s; nbase = NFULL + (long)(1036 - s) * (s - 1013) / 2; }
        float* ob = out + ((size_t)b * NSPAN + nbase) * NCOL + j;
#pragma unroll
        for (int k = 0; k < 12; ++k) {
            if (k < len) {
                f32x4 o = psf[t] + cvt4(pe[t + k]);
                __builtin_nontemporal_store(o, (f32x4*)(ob + (size_t)k * NCOL));
            }
        }
    }
}

// ======================= legacy direct path (fallback if ws too small) =======================
__global__ void mk_idx(int* __restrict__ sA, int* __restrict__ eA) {
    int n = blockIdx.x * 256 + threadIdx.x;
    if (n >= NPAD) return;
    int s = 0, e = 0;
    if (n < NFULL) {
        s = n / 12;
        e = s + (n - s * 12);
    } else if (n < NSPAN) {
        int r = n - NFULL;
        s = SEQLEN - 11;
        int cnt = 11;
        while (r >= cnt) { r -= cnt; --cnt; ++s; }
        e = s + r;
    }
    sA[n] = s; eA[n] = e;
}

__global__ __launch_bounds__(256) void span_gemm(
    const __bf16* __restrict__ Hbf,
    const __bf16* __restrict__ Wbf,
    const int*    __restrict__ idxS,
    const int*    __restrict__ idxE,
    const float*  __restrict__ bias,
    float*        __restrict__ out)
{
    __shared__ alignas(16) __bf16 As[128 * 32];
    __shared__ alignas(16) __bf16 Bs[128 * 32];

    const int tid  = threadIdx.x;
    const int wave = tid >> 6;
    const int lane = tid & 63;
    const int wm   = (wave >> 1) * 64;
    const int wn   = (wave & 1) * 64;
    const int lr   = lane & 15;
    const int lq   = lane >> 4;

    const int j0 = blockIdx.x * 128;
    const int n0 = blockIdx.y * 128;
    const int b  = blockIdx.z;

    const int l0  = wave * 1024 + lane * 8;
    const int l1  = l0 + 512;
    const int mm0 = l0 >> 5, kk0 = l0 & 31;
    const int mm1 = l1 >> 5, kk1 = l1 & 31;

    const int s0 = idxS[n0 + mm0], e0 = idxE[n0 + mm0];
    const int s1 = idxS[n0 + mm1], e1 = idxE[n0 + mm1];

    const __bf16* hb = Hbf + (size_t)b * (SEQLEN * HIDDEN);
    const __bf16* w0 = Wbf + (size_t)(j0 + mm0) * KDIM + kk0;
    const __bf16* w1 = Wbf + (size_t)(j0 + mm1) * KDIM + kk1;

    f32x4 acc[4][4];
#pragma unroll
    for (int i = 0; i < 4; ++i)
#pragma unroll
        for (int j = 0; j < 4; ++j)
            acc[i][j] = (f32x4){0.f, 0.f, 0.f, 0.f};

    for (int half = 0; half < 2; ++half) {
        const __bf16* a0  = hb + (half ? e0 : s0) * HIDDEN + kk0;
        const __bf16* a1  = hb + (half ? e1 : s1) * HIDDEN + kk1;
        const __bf16* wb0 = w0 + half * HIDDEN;
        const __bf16* wb1 = w1 + half * HIDDEN;

        for (int ks = 0; ks < 8; ++ks) {
            const int c0 = ks * 32;
            __syncthreads();
            load16(a0  + c0, &As[l0]);
            load16(a1  + c0, &As[l1]);
            load16(wb0 + c0, &Bs[l0]);
            load16(wb1 + c0, &Bs[l1]);
            __syncthreads();

            bf16x8 af[4], bfv[4];
#pragma unroll
            for (int mi = 0; mi < 4; ++mi)
                af[mi] = *(const bf16x8*)(As + (wm + mi * 16 + lr) * 32 + lq * 8);
#pragma unroll
            for (int ni = 0; ni < 4; ++ni)
                bfv[ni] = *(const bf16x8*)(Bs + (wn + ni * 16 + lr) * 32 + lq * 8);
#pragma unroll
            for (int mi = 0; mi < 4; ++mi)
#pragma unroll
                for (int ni = 0; ni < 4; ++ni)
                    acc[mi][ni] = __builtin_amdgcn_mfma_f32_16x16x32_bf16(
                        af[mi], bfv[ni], acc[mi][ni], 0, 0, 0);
        }
    }

    float bv[4];
#pragma unroll
    for (int ni = 0; ni < 4; ++ni) bv[ni] = bias[j0 + wn + ni * 16 + lr];

    const size_t obase = (size_t)b * NSPAN * NCOL;
#pragma unroll
    for (int mi = 0; mi < 4; ++mi) {
#pragma unroll
        for (int r = 0; r < 4; ++r) {
            const int n = n0 + wm + mi * 16 + lq * 4 + r;
            if (n < NSPAN) {
                float* op = out + obase + (size_t)n * NCOL + (j0 + wn + lr);
#pragma unroll
                for (int ni = 0; ni < 4; ++ni)
                    op[ni * 16] = acc[mi][ni][r] + bv[ni];
            }
        }
    }
}

extern "C" void kernel_launch(void* const* d_in, const int* in_sizes, int n_in,
                              void* d_out, int out_size, void* d_ws, size_t ws_size,
                              hipStream_t stream) {
    const float* hid  = (const float*)d_in[0];   // [8,1024,256]
    const float* W    = (const float*)d_in[1];   // [4,256,512]
    const float* bias = (const float*)d_in[2];   // [4,256] -> flat [1024]
    float* out = (float*)d_out;

    // ws layout: Wb (1 MB) | Hbf (4 MB) | P (bf16, nb batches) or idx tables
    char* ws = (char*)d_ws;
    __bf16* Wb  = (__bf16*)ws;
    __bf16* Hbf = (__bf16*)(ws + (size_t)1048576);
    const size_t base  = (size_t)1048576 + 4194304;            // 5.24 MB
    const size_t CHUNK = (size_t)SEQLEN * PCOLS * 2;           // 4 MB per batch

    // graded chunk ladder (unchanged from round 4 for attribution)
    int nb = 0;
    if      (ws_size >= base + 4 * CHUNK) nb = 4;              // 22.0 MB
    else if (ws_size >= base + 2 * CHUNK) nb = 2;              // 13.6 MB
    else if (ws_size >= base + 1 * CHUNK) nb = 1;              //  9.4 MB

    cvt_bf16<<<2048, 256, 0, stream>>>(hid, Hbf, MROWS * HIDDEN);

    if (nb) {
        __bf16* P = (__bf16*)(ws + base);
        mk_wbf2<<<512, 256, 0, stream>>>(W, Wb);
        for (int b0 = 0; b0 < BATCH; b0 += nb) {
            pgemm<<<dim3(nb * SEQLEN / 128, PCOLS / 128), 256, 0, stream>>>(
                Hbf + (size_t)b0 * SEQLEN * HIDDEN, Wb, bias, P);
            span_epi<<<nb * (SEQLEN / SB), 256, 0, stream>>>(P, out, b0);
        }
    } else {
        // legacy direct path (~5.34 MB ws). Marker question resolved (P-path
        // confirmed running in round 4) -> back to a single launch.
        int* idxS = (int*)(ws + base);
        int* idxE = idxS + NPAD;
        cvt_bf16<<<512, 256, 0, stream>>>(W, Wb, NCOL * KDIM);
        mk_idx<<<NPAD / 256, 256, 0, stream>>>(idxS, idxE);
        span_gemm<<<dim3(8, 96, BATCH), 256, 0, stream>>>(Hbf, Wb, idxS, idxE, bias, out);
    }
}